// Round 19
// baseline (828.068 us; speedup 1.0000x reference)
//
#include <hip/hip_runtime.h>
#include <hip/hip_bf16.h>
#include <stdint.h>

typedef __attribute__((ext_vector_type(8))) short bf16x8;
typedef __attribute__((ext_vector_type(4))) float f32x4;
typedef unsigned int u32;
typedef unsigned short u16;

// ---------------- helpers ----------------
__device__ __forceinline__ u32 bf16_1(float x) {
    u32 u = __float_as_uint(x);
    return (u + 0x7fffu + ((u >> 16) & 1u)) >> 16;   // RNE to bf16
}
__device__ __forceinline__ u32 packbf(float a, float b) {
    return bf16_1(a) | (bf16_1(b) << 16);
}
__device__ __forceinline__ float bf2f(u16 v) {
    return __uint_as_float(((u32)v) << 16);
}
// XOR-swizzle involution for 128-elem (16-chunk) bf16 rows; same map on write & read.
__device__ __forceinline__ int swz16(int row, int chunk) {
    return (chunk & 8) | ((chunk ^ row) & 7);
}

typedef const __attribute__((address_space(1))) u32* gptr_t;
typedef __attribute__((address_space(3))) u32* lptr_t;
__device__ __forceinline__ void gload16(const u16* g, u16* l) {
    __builtin_amdgcn_global_load_lds((gptr_t)g, (lptr_t)l, 16, 0, 0);
}

// ============ 128x128 BK=64 8-phase GEMM (r16) + optional fused SiLU ============
// 256 threads = 4 waves (2M x 2N), per-wave 64x64 out, acc[4][4]. LDS 64 KB dbuf.
// FUSESILU: B gate/up interleaved in 32-row groups; nf pairs (0,1),(2,3):
// out[row][((pcol>>5)<<4)+rl] = silu(gate)*up (fp32), bf16 to C[1024][ldc].
template<typename OUT, bool FUSESILU = false>
__global__ __launch_bounds__(256) void bgemm_kernel(
    const u16* __restrict__ A, int lda, long zA,
    const u16* __restrict__ B, int ldb, long zB,
    OUT* __restrict__ C, int ldc, long zC,
    int K)
{
    __shared__ __align__(16) u16 lds[32768];   // [2][ A 8192 | B 8192 ] elems
    const int z = blockIdx.z;
    A += (long)z * zA;
    B += (long)z * zB;
    C += (long)z * zC;

    const int gx = gridDim.x, gy = gridDim.y;
    int tm, tn;
    if (gx == 8) {                   // T1 panel swizzle (all grids nwg%8==0)
        int id = blockIdx.y * gx + blockIdx.x;
        int nwg8 = (gx * gy) >> 3;
        int lin = (id & 7) * nwg8 + (id >> 3);
        int span = gy << 2;
        int pp = lin / span;
        int rem = lin - pp * span;
        tn = rem >> 2;
        tm = (pp << 2) + (rem & 3);
    } else { tm = blockIdx.x; tn = blockIdx.y; }
    const int m0 = tm * 128, n0 = tn * 128;

    const int tid = threadIdx.x;
    const int lane = tid & 63, wave = tid >> 6;
    const int wm = wave >> 1, wn = wave & 1;          // 2M x 2N
    const int rl = lane & 15, gg = lane >> 4;
    const int srow = lane >> 3, schunk = lane & 7;
    const int NT = K >> 6;

    f32x4 acc[4][4];
#pragma unroll
    for (int i = 0; i < 4; ++i)
#pragma unroll
        for (int j = 0; j < 4; ++j) acc[i][j] = (f32x4){0.f, 0.f, 0.f, 0.f};

    const u16* Abase = A + (long)m0 * lda;
    const u16* Bbase = B + (long)n0 * ldb;

    auto stage_unit = [&](int t, int unit, int buf) {
        u16* base = lds + buf * 16384 + ((unit & 1) ? 8192 : 0);
        const u16* gsrc = (unit & 1) ? Bbase : Abase;
        const int ld = (unit & 1) ? ldb : lda;
        const int hofs = (unit == 1 || unit == 2) ? 32 : 0;
#pragma unroll
        for (int j = 0; j < 2; ++j) {
            int ii = wave * 2 + j;               // 0..7
            int rowbase = (ii >> 2) * 64 + hofs + (ii & 3) * 8;
            gload16(gsrc + (long)(rowbase + srow) * ld + t * 64 + ((schunk ^ srow) << 3),
                    base + rowbase * 64);
        }
    };
    bf16x8 afr[2][2], bqr[2][2], bqr2[2][2];
    auto readA = [&](const u16* Al, int mh, bf16x8 (&af)[2][2]) {
#pragma unroll
        for (int mf = 0; mf < 2; ++mf) {
            int row = wm * 64 + (mh * 2 + mf) * 16 + rl;
#pragma unroll
            for (int kk = 0; kk < 2; ++kk)
                af[mf][kk] = *reinterpret_cast<const bf16x8*>(
                    &Al[row * 64 + (((kk * 4 + gg) ^ (row & 7)) << 3)]);
        }
    };
    auto readB = [&](const u16* Bl, int nh, bf16x8 (&bq)[2][2]) {
#pragma unroll
        for (int nf = 0; nf < 2; ++nf) {
            int row = wn * 64 + (nh * 2 + nf) * 16 + rl;
#pragma unroll
            for (int kk = 0; kk < 2; ++kk)
                bq[nf][kk] = *reinterpret_cast<const bf16x8*>(
                    &Bl[row * 64 + (((kk * 4 + gg) ^ (row & 7)) << 3)]);
        }
    };
    auto mfma8 = [&](int mb, int nb, bf16x8 (&af)[2][2], bf16x8 (&bq)[2][2]) {
        __builtin_amdgcn_s_setprio(1);
#pragma unroll
        for (int kk = 0; kk < 2; ++kk)
#pragma unroll
            for (int mf = 0; mf < 2; ++mf)
#pragma unroll
                for (int nf = 0; nf < 2; ++nf)
                    acc[mb + mf][nb + nf] = __builtin_amdgcn_mfma_f32_16x16x32_bf16(
                        af[mf][kk], bq[nf][kk], acc[mb + mf][nb + nf], 0, 0, 0);
        __builtin_amdgcn_s_setprio(0);
    };

    stage_unit(0, 0, 0); stage_unit(0, 1, 0); stage_unit(0, 2, 0); stage_unit(0, 3, 0);
    stage_unit(1, 0, 1); stage_unit(1, 1, 1); stage_unit(1, 2, 1);
    asm volatile("s_waitcnt vmcnt(6)" ::: "memory");
    __builtin_amdgcn_s_barrier();

    const u16* Al0 = lds;
    const u16* Bl0 = lds + 8192;
    const u16* Al1 = lds + 16384;
    const u16* Bl1 = lds + 24576;

    for (int it = 0; it < (NT >> 1); ++it) {
        const int T = 2 * it;
        const bool more = (T + 2 < NT);
        readA(Al0, 0, afr); readB(Bl0, 0, bqr);
        stage_unit(T + 1, 3, 1);
        __builtin_amdgcn_s_barrier();
        asm volatile("s_waitcnt lgkmcnt(0)" ::: "memory");
        mfma8(0, 0, afr, bqr);
        __builtin_amdgcn_s_barrier();
        readB(Bl0, 1, bqr2);
        if (more) stage_unit(T + 2, 0, 0);
        __builtin_amdgcn_s_barrier();
        asm volatile("s_waitcnt lgkmcnt(0)" ::: "memory");
        mfma8(0, 2, afr, bqr2);
        __builtin_amdgcn_s_barrier();
        readA(Al0, 1, afr);
        if (more) stage_unit(T + 2, 1, 0);
        __builtin_amdgcn_s_barrier();
        asm volatile("s_waitcnt lgkmcnt(0)" ::: "memory");
        mfma8(2, 2, afr, bqr2);
        __builtin_amdgcn_s_barrier();
        readB(Bl0, 0, bqr);
        if (more) stage_unit(T + 2, 2, 0);
        __builtin_amdgcn_s_barrier();
        asm volatile("s_waitcnt lgkmcnt(0)" ::: "memory");
        mfma8(2, 0, afr, bqr);
        if (more) { asm volatile("s_waitcnt vmcnt(6)" ::: "memory"); }
        else      { asm volatile("s_waitcnt vmcnt(0)" ::: "memory"); }
        __builtin_amdgcn_s_barrier();
        readA(Al1, 0, afr); readB(Bl1, 0, bqr);
        if (more) stage_unit(T + 2, 3, 0);
        __builtin_amdgcn_s_barrier();
        asm volatile("s_waitcnt lgkmcnt(0)" ::: "memory");
        mfma8(0, 0, afr, bqr);
        __builtin_amdgcn_s_barrier();
        readB(Bl1, 1, bqr2);
        if (more) stage_unit(T + 3, 0, 1);
        __builtin_amdgcn_s_barrier();
        asm volatile("s_waitcnt lgkmcnt(0)" ::: "memory");
        mfma8(0, 2, afr, bqr2);
        __builtin_amdgcn_s_barrier();
        readA(Al1, 1, afr);
        if (more) stage_unit(T + 3, 1, 1);
        __builtin_amdgcn_s_barrier();
        asm volatile("s_waitcnt lgkmcnt(0)" ::: "memory");
        mfma8(2, 2, afr, bqr2);
        __builtin_amdgcn_s_barrier();
        readB(Bl1, 0, bqr);
        if (more) stage_unit(T + 3, 2, 1);
        __builtin_amdgcn_s_barrier();
        asm volatile("s_waitcnt lgkmcnt(0)" ::: "memory");
        mfma8(2, 0, afr, bqr);
        if (more) { asm volatile("s_waitcnt vmcnt(6)" ::: "memory"); }
        __builtin_amdgcn_s_barrier();
    }

    if constexpr (FUSESILU) {
#pragma unroll
        for (int mf = 0; mf < 4; ++mf) {
#pragma unroll
            for (int np = 0; np < 2; ++np) {
                int pcol = n0 + wn * 64 + np * 32;          // multiple of 32
                int gl = ((pcol >> 5) << 4) + rl;           // logical silu col
#pragma unroll
                for (int rr = 0; rr < 4; ++rr) {
                    int row = m0 + wm * 64 + mf * 16 + gg * 4 + rr;
                    float g = acc[mf][np * 2][rr];
                    float u = acc[mf][np * 2 + 1][rr];
                    float v = (g / (1.0f + __expf(-g))) * u;
                    ((u16*)C)[(long)row * ldc + gl] = (u16)bf16_1(v);
                }
            }
        }
    } else {
#pragma unroll
        for (int mf = 0; mf < 4; ++mf) {
#pragma unroll
            for (int nf = 0; nf < 4; ++nf) {
                int col = n0 + wn * 64 + nf * 16 + rl;
#pragma unroll
                for (int r = 0; r < 4; ++r) {
                    int row = m0 + wm * 64 + mf * 16 + gg * 4 + r;
                    long idx = (long)row * ldc + col;
                    float v = acc[mf][nf][r];
                    if constexpr (sizeof(OUT) == 2) ((u16*)C)[idx] = (u16)bf16_1(v);
                    else C[idx] = v;
                }
            }
        }
    }
}

// ============ flash attention (r13 staged config, best measured) ============
__global__ __launch_bounds__(128) void flash_kernel(
    const u16* __restrict__ qkv, const u16* __restrict__ kf,
    const u16* __restrict__ vfT, u16* __restrict__ attn)
{
    __shared__ __align__(16) u16 Ks[128 * 128];
    __shared__ __align__(16) u16 Vs[128 * 128];
    __shared__ __align__(16) u16 Ps[32 * 128];
    const int id = blockIdx.y * gridDim.x + blockIdx.x;
    const int lin = (id & 7) * 64 + (id >> 3);
    const int h = lin >> 5;
    const int q0 = (lin & 31) * 32;
    const int t = threadIdx.x;
    const int lane = t & 63, w = t >> 6;
    const int rl = lane & 15, gg = lane >> 4;
    const int qg = q0 + w * 16 + rl;
    const int qrow = w * 16 + rl;
    const int srow = t >> 4, schunk = t & 15;

    bf16x8 qf[4];
#pragma unroll
    for (int kk = 0; kk < 4; ++kk)
        qf[kk] = *reinterpret_cast<const bf16x8*>(qkv + (long)qg * 3072 + h * 128 + kk * 32 + gg * 8);

    f32x4 o[8];
#pragma unroll
    for (int i = 0; i < 8; ++i) o[i] = (f32x4){0.f, 0.f, 0.f, 0.f};
    float m = -INFINITY, l = 0.f;

    const int cs = q0 & ~511;
    const int ntiles = 16 + ((q0 - cs + 159) >> 7);

    for (int tt = 0; tt < ntiles; ++tt) {
        const int tb = (tt < 16) ? tt * 128 : (2048 + cs + (tt - 16) * 128);
#pragma unroll
        for (int i = 0; i < 16; ++i) {
            int row = i * 8 + srow;
            int cw = swz16(row, schunk) * 8;
            gload16(kf + ((long)(h * 3072 + tb + row)) * 128 + cw, &Ks[i * 1024 + w * 512]);
        }
#pragma unroll
        for (int i = 0; i < 16; ++i) {
            int row = i * 8 + srow;
            int cw = swz16(row, schunk) * 8;
            gload16(vfT + ((long)(h * 128 + row)) * 3072 + tb + cw, &Vs[i * 1024 + w * 512]);
        }
        __syncthreads();
        f32x4 s[8];
#pragma unroll
        for (int f = 0; f < 8; ++f) s[f] = (f32x4){0.f, 0.f, 0.f, 0.f};
#pragma unroll
        for (int kk = 0; kk < 4; ++kk) {
#pragma unroll
            for (int f = 0; f < 8; ++f) {
                int row = f * 16 + rl;
                bf16x8 kfrag = *reinterpret_cast<const bf16x8*>(
                    &Ks[row * 128 + swz16(row, kk * 4 + gg) * 8]);
                s[f] = __builtin_amdgcn_mfma_f32_16x16x32_bf16(kfrag, qf[kk], s[f], 0, 0, 0);
            }
        }
        float tm = -INFINITY;
#pragma unroll
        for (int f = 0; f < 8; ++f) {
#pragma unroll
            for (int r = 0; r < 4; ++r) {
                float v = s[f][r] * 0.08838834764831845f;
                if (tt >= 16) {
                    int jloc = (tb - 2048) + f * 16 + gg * 4 + r;
                    if (jloc > qg) v = -INFINITY;
                }
                s[f][r] = v;
                tm = fmaxf(tm, v);
            }
        }
        tm = fmaxf(tm, __shfl_xor(tm, 16));
        tm = fmaxf(tm, __shfl_xor(tm, 32));
        float mnew = fmaxf(m, tm);
        float alpha = __expf(m - mnew);
        m = mnew;
        float ts = 0.f;
#pragma unroll
        for (int f = 0; f < 8; ++f) {
#pragma unroll
            for (int r = 0; r < 4; ++r) {
                float e = __expf(s[f][r] - m);
                s[f][r] = e;
                ts += e;
            }
        }
        ts += __shfl_xor(ts, 16);
        ts += __shfl_xor(ts, 32);
        l = l * alpha + ts;
#pragma unroll
        for (int i = 0; i < 8; ++i)
#pragma unroll
            for (int r = 0; r < 4; ++r) o[i][r] *= alpha;
#pragma unroll
        for (int f = 0; f < 8; ++f) {
            int kvb = f * 16 + gg * 4;
            u32* dst = (u32*)&Ps[qrow * 128 + swz16(qrow, kvb >> 3) * 8 + (kvb & 7)];
            dst[0] = packbf(s[f][0], s[f][1]);
            dst[1] = packbf(s[f][2], s[f][3]);
        }
#pragma unroll
        for (int kk = 0; kk < 4; ++kk) {
            bf16x8 pfrag = *reinterpret_cast<const bf16x8*>(
                &Ps[qrow * 128 + swz16(qrow, kk * 4 + gg) * 8]);
#pragma unroll
            for (int fd = 0; fd < 8; ++fd) {
                int row = fd * 16 + rl;
                bf16x8 vfrag = *reinterpret_cast<const bf16x8*>(
                    &Vs[row * 128 + swz16(row, kk * 4 + gg) * 8]);
                o[fd] = __builtin_amdgcn_mfma_f32_16x16x32_bf16(vfrag, pfrag, o[fd], 0, 0, 0);
            }
        }
        __syncthreads();
    }
    float inv = 1.0f / l;
    u32* orow = (u32*)(attn + (long)qg * 2048 + h * 128);
#pragma unroll
    for (int fd = 0; fd < 8; ++fd) {
        int d0 = fd * 16 + gg * 4;
        orow[d0 >> 1]       = packbf(o[fd][0] * inv, o[fd][1] * inv);
        orow[(d0 >> 1) + 1] = packbf(o[fd][2] * inv, o[fd][3] * inv);
    }
}

// ============ transpose-convert body (shared); mode 0 = identity row map,
// mode 1 = gate interleave (row -> (r>>4)*32 + (r&15)),
// mode 2 = up interleave   (row -> (r>>4)*32 + 16 + (r&15)) ============
__device__ __forceinline__ void convT_body(const float* __restrict__ W, int ldw, int n0,
                                           u16* __restrict__ WT, int ldk, int bx, int by,
                                           int tthr, int mode) {
    __shared__ float tile[64][65];
    int c4 = tthr & 15, r0 = tthr >> 4;
    const float* src = W + (long)(by * 64 + r0) * ldw + n0 + bx * 64 + c4 * 4;
#pragma unroll
    for (int p = 0; p < 4; ++p) {
        float4 v = *reinterpret_cast<const float4*>(src + (long)(p * 16) * ldw);
        float* dst = &tile[r0 + p * 16][c4 * 4];
        dst[0] = v.x; dst[1] = v.y; dst[2] = v.z; dst[3] = v.w;
    }
    __syncthreads();
    int kp = tthr & 31, cc = tthr >> 5;
#pragma unroll
    for (int p = 0; p < 8; ++p) {
        int crow = cc + p * 8;
        int orow = bx * 64 + crow;
        if (mode == 1) orow = ((orow >> 4) << 5) + (orow & 15);
        else if (mode == 2) orow = ((orow >> 4) << 5) + 16 + (orow & 15);
        float a = tile[kp * 2][crow], b = tile[kp * 2 + 1][crow];
        ((u32*)WT)[(((long)orow * ldk + by * 64) >> 1) + kp] = packbf(a, b);
    }
}

// standalone convT (lm_head)
__global__ void convT_kernel(const float* __restrict__ W, int ldw, int n0,
                             u16* __restrict__ WT, int ldk) {
    convT_body(W, ldw, n0, WT, ldk, blockIdx.x, blockIdx.y, threadIdx.x, 0);
}

// merged per-layer conversion: 7 matrices, flat grid 11008 blocks
__global__ void convT_layer_kernel(
    const float* __restrict__ Wq, const float* __restrict__ Wk,
    const float* __restrict__ Wv, const float* __restrict__ Wo,
    const float* __restrict__ Wg, const float* __restrict__ Wu,
    const float* __restrict__ Wd,
    u16* __restrict__ qkvT, u16* __restrict__ WoT,
    u16* __restrict__ guT, u16* __restrict__ WdT)
{
    int i = blockIdx.x;
    const float* W; u16* WT; int ldw, ldk, gx, base, mode = 0;
    if (i < 1024)      { W = Wq; WT = qkvT;                 ldw = 2048; ldk = 2048; gx = 32; base = 0; }
    else if (i < 1280) { W = Wk; WT = qkvT + 2048 * 2048;   ldw = 512;  ldk = 2048; gx = 8;  base = 1024; }
    else if (i < 1536) { W = Wv; WT = qkvT + 2560 * 2048;   ldw = 512;  ldk = 2048; gx = 8;  base = 1280; }
    else if (i < 2560) { W = Wo; WT = WoT;                  ldw = 2048; ldk = 2048; gx = 32; base = 1536; }
    else if (i < 5376) { W = Wg; WT = guT;                  ldw = 5632; ldk = 2048; gx = 88; base = 2560; mode = 1; }
    else if (i < 8192) { W = Wu; WT = guT;                  ldw = 5632; ldk = 2048; gx = 88; base = 5376; mode = 2; }
    else               { W = Wd; WT = WdT;                  ldw = 2048; ldk = 5632; gx = 32; base = 8192; }
    int local = i - base;
    convT_body(W, ldw, 0, WT, ldk, local % gx, local / gx, threadIdx.x, mode);
}

// ---------------- fused embed + RMSNorm: x = emb[ids], h = rmsnorm(x)*w ----------------
__global__ void embed_rms_kernel(const int* __restrict__ ids, const float* __restrict__ emb,
                                 const float* __restrict__ w, float* __restrict__ x,
                                 u16* __restrict__ o) {
    int row = blockIdx.x, t = threadIdx.x;
    const float* er = emb + (long)ids[row] * 2048;
    float4 v0 = *reinterpret_cast<const float4*>(er + t * 4);
    float4 v1 = *reinterpret_cast<const float4*>(er + 1024 + t * 4);
    *reinterpret_cast<float4*>(x + (long)row * 2048 + t * 4) = v0;
    *reinterpret_cast<float4*>(x + (long)row * 2048 + 1024 + t * 4) = v1;
    float ss = v0.x * v0.x + v0.y * v0.y + v0.z * v0.z + v0.w * v0.w
             + v1.x * v1.x + v1.y * v1.y + v1.z * v1.z + v1.w * v1.w;
#pragma unroll
    for (int ofs = 32; ofs; ofs >>= 1) ss += __shfl_xor(ss, ofs);
    __shared__ float red[4];
    if ((t & 63) == 0) red[t >> 6] = ss;
    __syncthreads();
    ss = red[0] + red[1] + red[2] + red[3];
    float inv = 1.0f / sqrtf(ss * (1.0f / 2048.0f) + 1e-5f);
    float4 w0 = *reinterpret_cast<const float4*>(w + t * 4);
    float4 w1 = *reinterpret_cast<const float4*>(w + 1024 + t * 4);
    u32* op = (u32*)(o + (long)row * 2048);
    op[t * 2]           = packbf(v0.x * inv * w0.x, v0.y * inv * w0.y);
    op[t * 2 + 1]       = packbf(v0.z * inv * w0.z, v0.w * inv * w0.w);
    op[512 + t * 2]     = packbf(v1.x * inv * w1.x, v1.y * inv * w1.y);
    op[512 + t * 2 + 1] = packbf(v1.z * inv * w1.z, v1.w * inv * w1.w);
}

// ---------------- fused: x += p0 + p1 ; h = rmsnorm(x) * w ----------------
__global__ void rmsadd2_kernel(float* __restrict__ x, const float* __restrict__ p0,
                               const float* __restrict__ p1, const float* __restrict__ w,
                               u16* __restrict__ o) {
    int row = blockIdx.x, t = threadIdx.x;
    long base = (long)row * 2048;
    float4 v0 = *reinterpret_cast<const float4*>(x + base + t * 4);
    float4 v1 = *reinterpret_cast<const float4*>(x + base + 1024 + t * 4);
    float4 a0 = *reinterpret_cast<const float4*>(p0 + base + t * 4);
    float4 a1 = *reinterpret_cast<const float4*>(p0 + base + 1024 + t * 4);
    float4 b0 = *reinterpret_cast<const float4*>(p1 + base + t * 4);
    float4 b1 = *reinterpret_cast<const float4*>(p1 + base + 1024 + t * 4);
    v0.x += a0.x + b0.x; v0.y += a0.y + b0.y; v0.z += a0.z + b0.z; v0.w += a0.w + b0.w;
    v1.x += a1.x + b1.x; v1.y += a1.y + b1.y; v1.z += a1.z + b1.z; v1.w += a1.w + b1.w;
    *reinterpret_cast<float4*>(x + base + t * 4) = v0;
    *reinterpret_cast<float4*>(x + base + 1024 + t * 4) = v1;
    float ss = v0.x * v0.x + v0.y * v0.y + v0.z * v0.z + v0.w * v0.w
             + v1.x * v1.x + v1.y * v1.y + v1.z * v1.z + v1.w * v1.w;
#pragma unroll
    for (int ofs = 32; ofs; ofs >>= 1) ss += __shfl_xor(ss, ofs);
    __shared__ float red[4];
    if ((t & 63) == 0) red[t >> 6] = ss;
    __syncthreads();
    ss = red[0] + red[1] + red[2] + red[3];
    float inv = 1.0f / sqrtf(ss * (1.0f / 2048.0f) + 1e-5f);
    float4 w0 = *reinterpret_cast<const float4*>(w + t * 4);
    float4 w1 = *reinterpret_cast<const float4*>(w + 1024 + t * 4);
    u32* op = (u32*)(o + (long)row * 2048);
    op[t * 2]           = packbf(v0.x * inv * w0.x, v0.y * inv * w0.y);
    op[t * 2 + 1]       = packbf(v0.z * inv * w0.z, v0.w * inv * w0.w);
    op[512 + t * 2]     = packbf(v1.x * inv * w1.x, v1.y * inv * w1.y);
    op[512 + t * 2 + 1] = packbf(v1.z * inv * w1.z, v1.w * inv * w1.w);
}

// ============ merged rope_q + build_k + build_vT (mutually independent) ============
__global__ void prep_attn_kernel(u16* __restrict__ qkv,
                                 const float* __restrict__ kc, const float* __restrict__ vc,
                                 u16* __restrict__ kf, u16* __restrict__ vfT) {
    int blk = blockIdx.x;
    int tid = threadIdx.x;
    if (blk < 4096) {
        int idx = blk * 256 + tid;
        int fi = idx & 63;
        int hh = (idx >> 6) & 15;
        int s = idx >> 10;
        u16* p = qkv + (long)s * 3072 + hh * 128 + fi;
        float q0 = bf2f(p[0]), q1 = bf2f(p[64]);
        float inv = exp2f((float)fi * -0.20762050593046014f);
        float ang = (float)(2048 + s) * inv;
        float sn, cs;
        sincosf(ang, &sn, &cs);
        p[0]  = (u16)bf16_1(q0 * cs - q1 * sn);
        p[64] = (u16)bf16_1(q1 * cs + q0 * sn);
    } else if (blk < 16384) {
        int local = blk - 4096;
        int bx = local % 768, hh = local / 768;
        int t = bx * 256 + tid;
        int fi = t & 63;
        int j = t >> 6;
        float k0, k1;
        if (j < 2048) {
            const float* kp = kc + ((long)hh * 2048 + j) * 128;
            k0 = kp[fi]; k1 = kp[fi + 64];
        } else {
            int s = j - 2048;
            const u16* kp = qkv + (long)s * 3072 + 2048 + (hh >> 2) * 128;
            k0 = bf2f(kp[fi]); k1 = bf2f(kp[fi + 64]);
        }
        float inv = exp2f((float)fi * -0.20762050593046014f);
        float ang = (float)j * inv;
        float sn, cs;
        sincosf(ang, &sn, &cs);
        u16* kd = kf + ((long)hh * 3072 + j) * 128;
        kd[fi]      = (u16)bf16_1(k0 * cs - k1 * sn);
        kd[fi + 64] = (u16)bf16_1(k1 * cs + k0 * sn);
    } else {
        __shared__ u16 tile[64][137];
        int local = blk - 16384;
        int bx = local % 48, hh = local / 48;
        int j0 = bx * 64;
        int d = tid & 127, jr = tid >> 7;
#pragma unroll
        for (int p = 0; p < 32; ++p) {
            int j = jr + p * 2;
            int gj = j0 + j;
            float v;
            if (gj < 2048) v = vc[((long)hh * 2048 + gj) * 128 + d];
            else           v = bf2f(qkv[(long)(gj - 2048) * 3072 + 2560 + (hh >> 2) * 128 + d]);
            tile[j][d] = (u16)bf16_1(v);
        }
        __syncthreads();
        int jp = tid & 31, dd = tid >> 5;
#pragma unroll
        for (int p = 0; p < 16; ++p) {
            int d2 = dd + p * 8;
            u32 w = (u32)tile[jp * 2][d2] | ((u32)tile[jp * 2 + 1][d2] << 16);
            ((u32*)vfT)[((long)hh * 128 + d2) * 1536 + (j0 >> 1) + jp] = w;
        }
    }
}

// ---------------- host ----------------
extern "C" void kernel_launch(void* const* d_in, const int* in_sizes, int n_in,
                              void* d_out, int out_size, void* d_ws, size_t ws_size,
                              hipStream_t stream) {
    const int*   ids   = (const int*)d_in[0];
    const float* kv    = (const float*)d_in[1];
    const float* emb   = (const float*)d_in[2];
    const float* Wq    = (const float*)d_in[3];
    const float* Wk    = (const float*)d_in[4];
    const float* Wv    = (const float*)d_in[5];
    const float* Wo    = (const float*)d_in[6];
    const float* ln1   = (const float*)d_in[7];
    const float* ln2   = (const float*)d_in[8];
    const float* Wg    = (const float*)d_in[9];
    const float* Wu    = (const float*)d_in[10];
    const float* Wd    = (const float*)d_in[11];
    const float* normw = (const float*)d_in[12];
    const float* lmh   = (const float*)d_in[13];
    float* out = (float*)d_out;
    (void)in_sizes; (void)n_in; (void)out_size; (void)ws_size;

    char* w = (char*)d_ws;
    u16*   wt     = (u16*)w;                      // per-layer bf16^T weights (90.2 MB)
    float* x      = (float*)(w + 90177536);       // [1024,2048] fp32 residual
    u16*   h      = (u16*)(w + 98566144);         // [1024,2048] bf16
    u16*   qkv    = (u16*)(w + 102760448);        // [1024,3072] bf16 (layers only)
    u16*   kf     = (u16*)(w + 109051904);        // [16,3072,128] bf16
    u16*   vfT    = (u16*)(w + 121634816);        // [16,128,3072] bf16
    float* partWo = (float*)(w + 134217728);      // 2x[1024,2048] fp32
    u16*   gu     = (u16*)(w + 134217728);        // [1024,5632] bf16 (after Wo reduce)
    float* partWd = (float*)(w + 157286400);      // 2x[1024,2048] fp32
    u16*   attn   = (u16*)(w + 174063616);        // [1024,2048] bf16 (flash reads qkv!)
    u16*   lmT    = (u16*)(w + 102760448);        // [32000][2048] bf16 post-layers (131 MB)

    u16* qkvT = wt;                 // [3072][2048]
    u16* WoT  = wt + 6291456;       // [2048][2048]
    u16* guT  = wt + 10485760;      // [11264][2048] (gate/up interleaved 32-row groups)
    u16* WdT  = wt + 33554432;      // [2048][5632]

    embed_rms_kernel<<<1024, 256, 0, stream>>>(ids, emb, ln1, x, h);

    for (int l = 0; l < 2; ++l) {
        const float* Wq_l = Wq + (long)l * 2048 * 2048;
        const float* Wk_l = Wk + (long)l * 2048 * 512;
        const float* Wv_l = Wv + (long)l * 2048 * 512;
        const float* Wo_l = Wo + (long)l * 2048 * 2048;
        const float* Wg_l = Wg + (long)l * 2048 * 5632;
        const float* Wu_l = Wu + (long)l * 2048 * 5632;
        const float* Wd_l = Wd + (long)l * 5632 * 2048;
        const float* kc = kv + (long)l * 16 * 2048 * 128;
        const float* vc = kv + (long)(2 + l) * 16 * 2048 * 128;

        convT_layer_kernel<<<11008, 256, 0, stream>>>(
            Wq_l, Wk_l, Wv_l, Wo_l, Wg_l, Wu_l, Wd_l, qkvT, WoT, guT, WdT);

        // fused QKV projection: [1024,3072] on the 8-phase 128x128 engine
        bgemm_kernel<u16><<<dim3(8, 24, 1), 256, 0, stream>>>(
            h, 2048, 0, qkvT, 2048, 0, qkv, 3072, 0, 2048);
        // rope(q) + build K + build V^T in one launch
        prep_attn_kernel<<<17152, 256, 0, stream>>>(qkv, kc, vc, kf, vfT);

        // fused attention (scores+mask+softmax+PV), staged K/V
        flash_kernel<<<dim3(32, 16), 128, 0, stream>>>(qkv, kf, vfT, attn);

        // Wo with split-K, partials then fused add+rmsnorm(ln2)
        bgemm_kernel<float><<<dim3(8, 16, 2), 256, 0, stream>>>(
            attn, 2048, 1024, WoT, 2048, 1024,
            partWo, 2048, (long)1024 * 2048, 1024);
        rmsadd2_kernel<<<1024, 256, 0, stream>>>(x, partWo, partWo + 2097152, ln2 + l * 2048, h);

        // fused gate+up+SiLU on the 8-phase 128x128 engine (704 blocks)
        bgemm_kernel<u16, true><<<dim3(8, 88, 1), 256, 0, stream>>>(
            h, 2048, 0, guT, 2048, 0, gu, 5632, 0, 2048);

        // Wd with split-K, partials then fused add+rmsnorm(next norm weight)
        bgemm_kernel<float><<<dim3(8, 16, 2), 256, 0, stream>>>(
            gu, 5632, 2816, WdT, 5632, 2816,
            partWd, 2048, (long)1024 * 2048, 2816);
        rmsadd2_kernel<<<1024, 256, 0, stream>>>(
            x, partWd, partWd + 2097152, (l == 0) ? (ln1 + 2048) : normw, h);
    }

    // lm_head on the 8-phase 128x128 engine (grid 8x250 = 2000 blocks)
    convT_kernel<<<dim3(500, 32), 256, 0, stream>>>(lmh, 32000, 0, lmT, 2048);
    bgemm_kernel<float><<<dim3(8, 250, 1), 256, 0, stream>>>(
        h, 2048, 0, lmT, 2048, 0, out, 32000, 0, 2048);
}

// Round 20
// 796.230 us; speedup vs baseline: 1.0400x; 1.0400x over previous
//
#include <hip/hip_runtime.h>
#include <hip/hip_bf16.h>
#include <stdint.h>

typedef __attribute__((ext_vector_type(8))) short bf16x8;
typedef __attribute__((ext_vector_type(4))) float f32x4;
typedef unsigned int u32;
typedef unsigned short u16;

// ---------------- helpers ----------------
__device__ __forceinline__ u32 bf16_1(float x) {
    u32 u = __float_as_uint(x);
    return (u + 0x7fffu + ((u >> 16) & 1u)) >> 16;   // RNE to bf16
}
__device__ __forceinline__ u32 packbf(float a, float b) {
    return bf16_1(a) | (bf16_1(b) << 16);
}
__device__ __forceinline__ float bf2f(u16 v) {
    return __uint_as_float(((u32)v) << 16);
}
// XOR-swizzle involution for 128-elem (16-chunk) bf16 rows; same map on write & read.
__device__ __forceinline__ int swz16(int row, int chunk) {
    return (chunk & 8) | ((chunk ^ row) & 7);
}

typedef const __attribute__((address_space(1))) u32* gptr_t;
typedef __attribute__((address_space(3))) u32* lptr_t;
__device__ __forceinline__ void gload16(const u16* g, u16* l) {
    __builtin_amdgcn_global_load_lds((gptr_t)g, (lptr_t)l, 16, 0, 0);
}

// ============ 128x128 BK=64 8-phase GEMM (r16) + optional fused SiLU ============
// 256 threads = 4 waves (2M x 2N), per-wave 64x64 out, acc[4][4]. LDS 64 KB dbuf.
// FUSESILU: B gate/up interleaved in 32-row groups; nf pairs (0,1),(2,3):
// out[row][((pcol>>5)<<4)+rl] = silu(gate)*up (fp32), bf16 to C[1024][ldc].
template<typename OUT, bool FUSESILU = false>
__global__ __launch_bounds__(256) void bgemm_kernel(
    const u16* __restrict__ A, int lda, long zA,
    const u16* __restrict__ B, int ldb, long zB,
    OUT* __restrict__ C, int ldc, long zC,
    int K)
{
    __shared__ __align__(16) u16 lds[32768];   // [2][ A 8192 | B 8192 ] elems
    const int z = blockIdx.z;
    A += (long)z * zA;
    B += (long)z * zB;
    C += (long)z * zC;

    const int gx = gridDim.x, gy = gridDim.y;
    int tm, tn;
    if (gx == 8) {                   // T1 panel swizzle (all grids nwg%8==0)
        int id = blockIdx.y * gx + blockIdx.x;
        int nwg8 = (gx * gy) >> 3;
        int lin = (id & 7) * nwg8 + (id >> 3);
        int span = gy << 2;
        int pp = lin / span;
        int rem = lin - pp * span;
        tn = rem >> 2;
        tm = (pp << 2) + (rem & 3);
    } else { tm = blockIdx.x; tn = blockIdx.y; }
    const int m0 = tm * 128, n0 = tn * 128;

    const int tid = threadIdx.x;
    const int lane = tid & 63, wave = tid >> 6;
    const int wm = wave >> 1, wn = wave & 1;          // 2M x 2N
    const int rl = lane & 15, gg = lane >> 4;
    const int srow = lane >> 3, schunk = lane & 7;
    const int NT = K >> 6;

    f32x4 acc[4][4];
#pragma unroll
    for (int i = 0; i < 4; ++i)
#pragma unroll
        for (int j = 0; j < 4; ++j) acc[i][j] = (f32x4){0.f, 0.f, 0.f, 0.f};

    const u16* Abase = A + (long)m0 * lda;
    const u16* Bbase = B + (long)n0 * ldb;

    auto stage_unit = [&](int t, int unit, int buf) {
        u16* base = lds + buf * 16384 + ((unit & 1) ? 8192 : 0);
        const u16* gsrc = (unit & 1) ? Bbase : Abase;
        const int ld = (unit & 1) ? ldb : lda;
        const int hofs = (unit == 1 || unit == 2) ? 32 : 0;
#pragma unroll
        for (int j = 0; j < 2; ++j) {
            int ii = wave * 2 + j;               // 0..7
            int rowbase = (ii >> 2) * 64 + hofs + (ii & 3) * 8;
            gload16(gsrc + (long)(rowbase + srow) * ld + t * 64 + ((schunk ^ srow) << 3),
                    base + rowbase * 64);
        }
    };
    bf16x8 afr[2][2], bqr[2][2], bqr2[2][2];
    auto readA = [&](const u16* Al, int mh, bf16x8 (&af)[2][2]) {
#pragma unroll
        for (int mf = 0; mf < 2; ++mf) {
            int row = wm * 64 + (mh * 2 + mf) * 16 + rl;
#pragma unroll
            for (int kk = 0; kk < 2; ++kk)
                af[mf][kk] = *reinterpret_cast<const bf16x8*>(
                    &Al[row * 64 + (((kk * 4 + gg) ^ (row & 7)) << 3)]);
        }
    };
    auto readB = [&](const u16* Bl, int nh, bf16x8 (&bq)[2][2]) {
#pragma unroll
        for (int nf = 0; nf < 2; ++nf) {
            int row = wn * 64 + (nh * 2 + nf) * 16 + rl;
#pragma unroll
            for (int kk = 0; kk < 2; ++kk)
                bq[nf][kk] = *reinterpret_cast<const bf16x8*>(
                    &Bl[row * 64 + (((kk * 4 + gg) ^ (row & 7)) << 3)]);
        }
    };
    auto mfma8 = [&](int mb, int nb, bf16x8 (&af)[2][2], bf16x8 (&bq)[2][2]) {
        __builtin_amdgcn_s_setprio(1);
#pragma unroll
        for (int kk = 0; kk < 2; ++kk)
#pragma unroll
            for (int mf = 0; mf < 2; ++mf)
#pragma unroll
                for (int nf = 0; nf < 2; ++nf)
                    acc[mb + mf][nb + nf] = __builtin_amdgcn_mfma_f32_16x16x32_bf16(
                        af[mf][kk], bq[nf][kk], acc[mb + mf][nb + nf], 0, 0, 0);
        __builtin_amdgcn_s_setprio(0);
    };

    stage_unit(0, 0, 0); stage_unit(0, 1, 0); stage_unit(0, 2, 0); stage_unit(0, 3, 0);
    stage_unit(1, 0, 1); stage_unit(1, 1, 1); stage_unit(1, 2, 1);
    asm volatile("s_waitcnt vmcnt(6)" ::: "memory");
    __builtin_amdgcn_s_barrier();

    const u16* Al0 = lds;
    const u16* Bl0 = lds + 8192;
    const u16* Al1 = lds + 16384;
    const u16* Bl1 = lds + 24576;

    for (int it = 0; it < (NT >> 1); ++it) {
        const int T = 2 * it;
        const bool more = (T + 2 < NT);
        readA(Al0, 0, afr); readB(Bl0, 0, bqr);
        stage_unit(T + 1, 3, 1);
        __builtin_amdgcn_s_barrier();
        asm volatile("s_waitcnt lgkmcnt(0)" ::: "memory");
        mfma8(0, 0, afr, bqr);
        __builtin_amdgcn_s_barrier();
        readB(Bl0, 1, bqr2);
        if (more) stage_unit(T + 2, 0, 0);
        __builtin_amdgcn_s_barrier();
        asm volatile("s_waitcnt lgkmcnt(0)" ::: "memory");
        mfma8(0, 2, afr, bqr2);
        __builtin_amdgcn_s_barrier();
        readA(Al0, 1, afr);
        if (more) stage_unit(T + 2, 1, 0);
        __builtin_amdgcn_s_barrier();
        asm volatile("s_waitcnt lgkmcnt(0)" ::: "memory");
        mfma8(2, 2, afr, bqr2);
        __builtin_amdgcn_s_barrier();
        readB(Bl0, 0, bqr);
        if (more) stage_unit(T + 2, 2, 0);
        __builtin_amdgcn_s_barrier();
        asm volatile("s_waitcnt lgkmcnt(0)" ::: "memory");
        mfma8(2, 0, afr, bqr);
        if (more) { asm volatile("s_waitcnt vmcnt(6)" ::: "memory"); }
        else      { asm volatile("s_waitcnt vmcnt(0)" ::: "memory"); }
        __builtin_amdgcn_s_barrier();
        readA(Al1, 0, afr); readB(Bl1, 0, bqr);
        if (more) stage_unit(T + 2, 3, 0);
        __builtin_amdgcn_s_barrier();
        asm volatile("s_waitcnt lgkmcnt(0)" ::: "memory");
        mfma8(0, 0, afr, bqr);
        __builtin_amdgcn_s_barrier();
        readB(Bl1, 1, bqr2);
        if (more) stage_unit(T + 3, 0, 1);
        __builtin_amdgcn_s_barrier();
        asm volatile("s_waitcnt lgkmcnt(0)" ::: "memory");
        mfma8(0, 2, afr, bqr2);
        __builtin_amdgcn_s_barrier();
        readA(Al1, 1, afr);
        if (more) stage_unit(T + 3, 1, 1);
        __builtin_amdgcn_s_barrier();
        asm volatile("s_waitcnt lgkmcnt(0)" ::: "memory");
        mfma8(2, 2, afr, bqr2);
        __builtin_amdgcn_s_barrier();
        readB(Bl1, 0, bqr);
        if (more) stage_unit(T + 3, 2, 1);
        __builtin_amdgcn_s_barrier();
        asm volatile("s_waitcnt lgkmcnt(0)" ::: "memory");
        mfma8(2, 0, afr, bqr);
        if (more) { asm volatile("s_waitcnt vmcnt(6)" ::: "memory"); }
        __builtin_amdgcn_s_barrier();
    }

    if constexpr (FUSESILU) {
#pragma unroll
        for (int mf = 0; mf < 4; ++mf) {
#pragma unroll
            for (int np = 0; np < 2; ++np) {
                int pcol = n0 + wn * 64 + np * 32;          // multiple of 32
                int gl = ((pcol >> 5) << 4) + rl;           // logical silu col
#pragma unroll
                for (int rr = 0; rr < 4; ++rr) {
                    int row = m0 + wm * 64 + mf * 16 + gg * 4 + rr;
                    float g = acc[mf][np * 2][rr];
                    float u = acc[mf][np * 2 + 1][rr];
                    float v = (g / (1.0f + __expf(-g))) * u;
                    ((u16*)C)[(long)row * ldc + gl] = (u16)bf16_1(v);
                }
            }
        }
    } else {
#pragma unroll
        for (int mf = 0; mf < 4; ++mf) {
#pragma unroll
            for (int nf = 0; nf < 4; ++nf) {
                int col = n0 + wn * 64 + nf * 16 + rl;
#pragma unroll
                for (int r = 0; r < 4; ++r) {
                    int row = m0 + wm * 64 + mf * 16 + gg * 4 + r;
                    long idx = (long)row * ldc + col;
                    float v = acc[mf][nf][r];
                    if constexpr (sizeof(OUT) == 2) ((u16*)C)[idx] = (u16)bf16_1(v);
                    else C[idx] = v;
                }
            }
        }
    }
}

// ============ 256x256 BK=64 8-phase GEMM (r12, best measured; lm_head) ============
template<typename OUT>
__global__ __launch_bounds__(512) void bgemm256_kernel(
    const u16* __restrict__ A, int lda,
    const u16* __restrict__ B, int ldb,
    OUT* __restrict__ C, int ldc,
    int K)
{
    __shared__ __align__(16) u16 lds[65536];    // [2][ A 16384 | B 16384 ]
    const int nwg = gridDim.x * gridDim.y;
    const int id = blockIdx.y * gridDim.x + blockIdx.x;
    const int xcd = id & 7, pos = id >> 3;
    const int q = nwg >> 3, r = nwg & 7;
    const int lin = (xcd < r ? xcd * (q + 1) : r * (q + 1) + (xcd - r) * q) + pos;
    const int tm = lin & 3, tn = lin >> 2;
    const int m0 = tm * 256, n0 = tn * 256;

    const int tid = threadIdx.x;
    const int lane = tid & 63, wave = tid >> 6;
    const int wm = wave >> 2, wn = wave & 3;          // 2M x 4N
    const int rl = lane & 15, gg = lane >> 4;
    const int srow = lane >> 3, schunk = lane & 7;
    const int NT = K >> 6;                            // even

    f32x4 acc[8][4];
#pragma unroll
    for (int i = 0; i < 8; ++i)
#pragma unroll
        for (int j = 0; j < 4; ++j) acc[i][j] = (f32x4){0.f, 0.f, 0.f, 0.f};

    const u16* Abase = A + (long)m0 * lda;
    const u16* Bbase = B + (long)n0 * ldb;

    auto stage_unit = [&](int t, int unit, int buf) {
        u16* base = lds + buf * 32768 + ((unit & 1) ? 16384 : 0);
        const u16* gsrc = (unit & 1) ? Bbase : Abase;
        const int ld = (unit & 1) ? ldb : lda;
#pragma unroll
        for (int j = 0; j < 2; ++j) {
            int ii = wave * 2 + j;               // 0..15
            int rowbase;
            if (unit & 1) rowbase = (ii >> 2) * 64 + ((unit == 1) ? 32 : 0) + (ii & 3) * 8;
            else          rowbase = (ii >> 3) * 128 + ((unit == 2) ? 64 : 0) + (ii & 7) * 8;
            gload16(gsrc + (long)(rowbase + srow) * ld + t * 64 + ((schunk ^ srow) << 3),
                    base + rowbase * 64);
        }
    };
    bf16x8 afr[4][2], bqr[2][2], bqr2[2][2];
    auto readA = [&](const u16* Al, int mh, bf16x8 (&af)[4][2]) {
#pragma unroll
        for (int mf = 0; mf < 4; ++mf) {
            int row = wm * 128 + (mh * 4 + mf) * 16 + rl;
#pragma unroll
            for (int kk = 0; kk < 2; ++kk)
                af[mf][kk] = *reinterpret_cast<const bf16x8*>(
                    &Al[row * 64 + (((kk * 4 + gg) ^ (row & 7)) << 3)]);
        }
    };
    auto readB = [&](const u16* Bl, int nh, bf16x8 (&bq)[2][2]) {
#pragma unroll
        for (int nf = 0; nf < 2; ++nf) {
            int row = wn * 64 + (nh * 2 + nf) * 16 + rl;
#pragma unroll
            for (int kk = 0; kk < 2; ++kk)
                bq[nf][kk] = *reinterpret_cast<const bf16x8*>(
                    &Bl[row * 64 + (((kk * 4 + gg) ^ (row & 7)) << 3)]);
        }
    };
    auto mfma16 = [&](int mb, int nb, bf16x8 (&af)[4][2], bf16x8 (&bq)[2][2]) {
        __builtin_amdgcn_s_setprio(1);
#pragma unroll
        for (int kk = 0; kk < 2; ++kk)
#pragma unroll
            for (int mf = 0; mf < 4; ++mf)
#pragma unroll
                for (int nf = 0; nf < 2; ++nf)
                    acc[mb + mf][nb + nf] = __builtin_amdgcn_mfma_f32_16x16x32_bf16(
                        af[mf][kk], bq[nf][kk], acc[mb + mf][nb + nf], 0, 0, 0);
        __builtin_amdgcn_s_setprio(0);
    };

    stage_unit(0, 0, 0); stage_unit(0, 1, 0); stage_unit(0, 2, 0); stage_unit(0, 3, 0);
    stage_unit(1, 0, 1); stage_unit(1, 1, 1); stage_unit(1, 2, 1);
    asm volatile("s_waitcnt vmcnt(6)" ::: "memory");
    __builtin_amdgcn_s_barrier();

    const u16* Al0 = lds;
    const u16* Bl0 = lds + 16384;
    const u16* Al1 = lds + 32768;
    const u16* Bl1 = lds + 49152;

    for (int it = 0; it < (NT >> 1); ++it) {
        const int T = 2 * it;
        const bool more = (T + 2 < NT);
        readA(Al0, 0, afr); readB(Bl0, 0, bqr);
        stage_unit(T + 1, 3, 1);
        __builtin_amdgcn_s_barrier();
        asm volatile("s_waitcnt lgkmcnt(0)" ::: "memory");
        mfma16(0, 0, afr, bqr);
        __builtin_amdgcn_s_barrier();
        readB(Bl0, 1, bqr2);
        if (more) stage_unit(T + 2, 0, 0);
        __builtin_amdgcn_s_barrier();
        asm volatile("s_waitcnt lgkmcnt(0)" ::: "memory");
        mfma16(0, 2, afr, bqr2);
        __builtin_amdgcn_s_barrier();
        readA(Al0, 1, afr);
        if (more) stage_unit(T + 2, 1, 0);
        __builtin_amdgcn_s_barrier();
        asm volatile("s_waitcnt lgkmcnt(0)" ::: "memory");
        mfma16(4, 2, afr, bqr2);
        __builtin_amdgcn_s_barrier();
        readB(Bl0, 0, bqr);
        if (more) stage_unit(T + 2, 2, 0);
        __builtin_amdgcn_s_barrier();
        asm volatile("s_waitcnt lgkmcnt(0)" ::: "memory");
        mfma16(4, 0, afr, bqr);
        if (more) { asm volatile("s_waitcnt vmcnt(6)" ::: "memory"); }
        else      { asm volatile("s_waitcnt vmcnt(0)" ::: "memory"); }
        __builtin_amdgcn_s_barrier();
        readA(Al1, 0, afr); readB(Bl1, 0, bqr);
        if (more) stage_unit(T + 2, 3, 0);
        __builtin_amdgcn_s_barrier();
        asm volatile("s_waitcnt lgkmcnt(0)" ::: "memory");
        mfma16(0, 0, afr, bqr);
        __builtin_amdgcn_s_barrier();
        readB(Bl1, 1, bqr2);
        if (more) stage_unit(T + 3, 0, 1);
        __builtin_amdgcn_s_barrier();
        asm volatile("s_waitcnt lgkmcnt(0)" ::: "memory");
        mfma16(0, 2, afr, bqr2);
        __builtin_amdgcn_s_barrier();
        readA(Al1, 1, afr);
        if (more) stage_unit(T + 3, 1, 1);
        __builtin_amdgcn_s_barrier();
        asm volatile("s_waitcnt lgkmcnt(0)" ::: "memory");
        mfma16(4, 2, afr, bqr2);
        __builtin_amdgcn_s_barrier();
        readB(Bl1, 0, bqr);
        if (more) stage_unit(T + 3, 2, 1);
        __builtin_amdgcn_s_barrier();
        asm volatile("s_waitcnt lgkmcnt(0)" ::: "memory");
        mfma16(4, 0, afr, bqr);
        if (more) { asm volatile("s_waitcnt vmcnt(6)" ::: "memory"); }
        __builtin_amdgcn_s_barrier();
    }

#pragma unroll
    for (int mf = 0; mf < 8; ++mf) {
#pragma unroll
        for (int nf = 0; nf < 4; ++nf) {
            int col = n0 + wn * 64 + nf * 16 + rl;
#pragma unroll
            for (int rr = 0; rr < 4; ++rr) {
                int row = m0 + wm * 128 + mf * 16 + gg * 4 + rr;
                long idx = (long)row * ldc + col;
                float v = acc[mf][nf][rr];
                if constexpr (sizeof(OUT) == 2) ((u16*)C)[idx] = (u16)bf16_1(v);
                else C[idx] = v;
            }
        }
    }
}

// ============ flash attention (r13 staged config, best measured) ============
__global__ __launch_bounds__(128) void flash_kernel(
    const u16* __restrict__ qkv, const u16* __restrict__ kf,
    const u16* __restrict__ vfT, u16* __restrict__ attn)
{
    __shared__ __align__(16) u16 Ks[128 * 128];
    __shared__ __align__(16) u16 Vs[128 * 128];
    __shared__ __align__(16) u16 Ps[32 * 128];
    const int id = blockIdx.y * gridDim.x + blockIdx.x;
    const int lin = (id & 7) * 64 + (id >> 3);
    const int h = lin >> 5;
    const int q0 = (lin & 31) * 32;
    const int t = threadIdx.x;
    const int lane = t & 63, w = t >> 6;
    const int rl = lane & 15, gg = lane >> 4;
    const int qg = q0 + w * 16 + rl;
    const int qrow = w * 16 + rl;
    const int srow = t >> 4, schunk = t & 15;

    bf16x8 qf[4];
#pragma unroll
    for (int kk = 0; kk < 4; ++kk)
        qf[kk] = *reinterpret_cast<const bf16x8*>(qkv + (long)qg * 3072 + h * 128 + kk * 32 + gg * 8);

    f32x4 o[8];
#pragma unroll
    for (int i = 0; i < 8; ++i) o[i] = (f32x4){0.f, 0.f, 0.f, 0.f};
    float m = -INFINITY, l = 0.f;

    const int cs = q0 & ~511;
    const int ntiles = 16 + ((q0 - cs + 159) >> 7);

    for (int tt = 0; tt < ntiles; ++tt) {
        const int tb = (tt < 16) ? tt * 128 : (2048 + cs + (tt - 16) * 128);
#pragma unroll
        for (int i = 0; i < 16; ++i) {
            int row = i * 8 + srow;
            int cw = swz16(row, schunk) * 8;
            gload16(kf + ((long)(h * 3072 + tb + row)) * 128 + cw, &Ks[i * 1024 + w * 512]);
        }
#pragma unroll
        for (int i = 0; i < 16; ++i) {
            int row = i * 8 + srow;
            int cw = swz16(row, schunk) * 8;
            gload16(vfT + ((long)(h * 128 + row)) * 3072 + tb + cw, &Vs[i * 1024 + w * 512]);
        }
        __syncthreads();
        f32x4 s[8];
#pragma unroll
        for (int f = 0; f < 8; ++f) s[f] = (f32x4){0.f, 0.f, 0.f, 0.f};
#pragma unroll
        for (int kk = 0; kk < 4; ++kk) {
#pragma unroll
            for (int f = 0; f < 8; ++f) {
                int row = f * 16 + rl;
                bf16x8 kfrag = *reinterpret_cast<const bf16x8*>(
                    &Ks[row * 128 + swz16(row, kk * 4 + gg) * 8]);
                s[f] = __builtin_amdgcn_mfma_f32_16x16x32_bf16(kfrag, qf[kk], s[f], 0, 0, 0);
            }
        }
        float tm = -INFINITY;
#pragma unroll
        for (int f = 0; f < 8; ++f) {
#pragma unroll
            for (int r = 0; r < 4; ++r) {
                float v = s[f][r] * 0.08838834764831845f;
                if (tt >= 16) {
                    int jloc = (tb - 2048) + f * 16 + gg * 4 + r;
                    if (jloc > qg) v = -INFINITY;
                }
                s[f][r] = v;
                tm = fmaxf(tm, v);
            }
        }
        tm = fmaxf(tm, __shfl_xor(tm, 16));
        tm = fmaxf(tm, __shfl_xor(tm, 32));
        float mnew = fmaxf(m, tm);
        float alpha = __expf(m - mnew);
        m = mnew;
        float ts = 0.f;
#pragma unroll
        for (int f = 0; f < 8; ++f) {
#pragma unroll
            for (int r = 0; r < 4; ++r) {
                float e = __expf(s[f][r] - m);
                s[f][r] = e;
                ts += e;
            }
        }
        ts += __shfl_xor(ts, 16);
        ts += __shfl_xor(ts, 32);
        l = l * alpha + ts;
#pragma unroll
        for (int i = 0; i < 8; ++i)
#pragma unroll
            for (int r = 0; r < 4; ++r) o[i][r] *= alpha;
#pragma unroll
        for (int f = 0; f < 8; ++f) {
            int kvb = f * 16 + gg * 4;
            u32* dst = (u32*)&Ps[qrow * 128 + swz16(qrow, kvb >> 3) * 8 + (kvb & 7)];
            dst[0] = packbf(s[f][0], s[f][1]);
            dst[1] = packbf(s[f][2], s[f][3]);
        }
#pragma unroll
        for (int kk = 0; kk < 4; ++kk) {
            bf16x8 pfrag = *reinterpret_cast<const bf16x8*>(
                &Ps[qrow * 128 + swz16(qrow, kk * 4 + gg) * 8]);
#pragma unroll
            for (int fd = 0; fd < 8; ++fd) {
                int row = fd * 16 + rl;
                bf16x8 vfrag = *reinterpret_cast<const bf16x8*>(
                    &Vs[row * 128 + swz16(row, kk * 4 + gg) * 8]);
                o[fd] = __builtin_amdgcn_mfma_f32_16x16x32_bf16(vfrag, pfrag, o[fd], 0, 0, 0);
            }
        }
        __syncthreads();
    }
    float inv = 1.0f / l;
    u32* orow = (u32*)(attn + (long)qg * 2048 + h * 128);
#pragma unroll
    for (int fd = 0; fd < 8; ++fd) {
        int d0 = fd * 16 + gg * 4;
        orow[d0 >> 1]       = packbf(o[fd][0] * inv, o[fd][1] * inv);
        orow[(d0 >> 1) + 1] = packbf(o[fd][2] * inv, o[fd][3] * inv);
    }
}

// ============ transpose-convert body (shared); mode 0 = identity row map,
// mode 1 = gate interleave (row -> (r>>4)*32 + (r&15)),
// mode 2 = up interleave   (row -> (r>>4)*32 + 16 + (r&15)) ============
__device__ __forceinline__ void convT_body(const float* __restrict__ W, int ldw, int n0,
                                           u16* __restrict__ WT, int ldk, int bx, int by,
                                           int tthr, int mode) {
    __shared__ float tile[64][65];
    int c4 = tthr & 15, r0 = tthr >> 4;
    const float* src = W + (long)(by * 64 + r0) * ldw + n0 + bx * 64 + c4 * 4;
#pragma unroll
    for (int p = 0; p < 4; ++p) {
        float4 v = *reinterpret_cast<const float4*>(src + (long)(p * 16) * ldw);
        float* dst = &tile[r0 + p * 16][c4 * 4];
        dst[0] = v.x; dst[1] = v.y; dst[2] = v.z; dst[3] = v.w;
    }
    __syncthreads();
    int kp = tthr & 31, cc = tthr >> 5;
#pragma unroll
    for (int p = 0; p < 8; ++p) {
        int crow = cc + p * 8;
        int orow = bx * 64 + crow;
        if (mode == 1) orow = ((orow >> 4) << 5) + (orow & 15);
        else if (mode == 2) orow = ((orow >> 4) << 5) + 16 + (orow & 15);
        float a = tile[kp * 2][crow], b = tile[kp * 2 + 1][crow];
        ((u32*)WT)[(((long)orow * ldk + by * 64) >> 1) + kp] = packbf(a, b);
    }
}

// standalone convT (lm_head)
__global__ void convT_kernel(const float* __restrict__ W, int ldw, int n0,
                             u16* __restrict__ WT, int ldk) {
    convT_body(W, ldw, n0, WT, ldk, blockIdx.x, blockIdx.y, threadIdx.x, 0);
}

// merged per-layer conversion: 7 matrices, flat grid 11008 blocks
__global__ void convT_layer_kernel(
    const float* __restrict__ Wq, const float* __restrict__ Wk,
    const float* __restrict__ Wv, const float* __restrict__ Wo,
    const float* __restrict__ Wg, const float* __restrict__ Wu,
    const float* __restrict__ Wd,
    u16* __restrict__ qkvT, u16* __restrict__ WoT,
    u16* __restrict__ guT, u16* __restrict__ WdT)
{
    int i = blockIdx.x;
    const float* W; u16* WT; int ldw, ldk, gx, base, mode = 0;
    if (i < 1024)      { W = Wq; WT = qkvT;                 ldw = 2048; ldk = 2048; gx = 32; base = 0; }
    else if (i < 1280) { W = Wk; WT = qkvT + 2048 * 2048;   ldw = 512;  ldk = 2048; gx = 8;  base = 1024; }
    else if (i < 1536) { W = Wv; WT = qkvT + 2560 * 2048;   ldw = 512;  ldk = 2048; gx = 8;  base = 1280; }
    else if (i < 2560) { W = Wo; WT = WoT;                  ldw = 2048; ldk = 2048; gx = 32; base = 1536; }
    else if (i < 5376) { W = Wg; WT = guT;                  ldw = 5632; ldk = 2048; gx = 88; base = 2560; mode = 1; }
    else if (i < 8192) { W = Wu; WT = guT;                  ldw = 5632; ldk = 2048; gx = 88; base = 5376; mode = 2; }
    else               { W = Wd; WT = WdT;                  ldw = 2048; ldk = 5632; gx = 32; base = 8192; }
    int local = i - base;
    convT_body(W, ldw, 0, WT, ldk, local % gx, local / gx, threadIdx.x, mode);
}

// ---------------- fused embed + RMSNorm: x = emb[ids], h = rmsnorm(x)*w ----------------
__global__ void embed_rms_kernel(const int* __restrict__ ids, const float* __restrict__ emb,
                                 const float* __restrict__ w, float* __restrict__ x,
                                 u16* __restrict__ o) {
    int row = blockIdx.x, t = threadIdx.x;
    const float* er = emb + (long)ids[row] * 2048;
    float4 v0 = *reinterpret_cast<const float4*>(er + t * 4);
    float4 v1 = *reinterpret_cast<const float4*>(er + 1024 + t * 4);
    *reinterpret_cast<float4*>(x + (long)row * 2048 + t * 4) = v0;
    *reinterpret_cast<float4*>(x + (long)row * 2048 + 1024 + t * 4) = v1;
    float ss = v0.x * v0.x + v0.y * v0.y + v0.z * v0.z + v0.w * v0.w
             + v1.x * v1.x + v1.y * v1.y + v1.z * v1.z + v1.w * v1.w;
#pragma unroll
    for (int ofs = 32; ofs; ofs >>= 1) ss += __shfl_xor(ss, ofs);
    __shared__ float red[4];
    if ((t & 63) == 0) red[t >> 6] = ss;
    __syncthreads();
    ss = red[0] + red[1] + red[2] + red[3];
    float inv = 1.0f / sqrtf(ss * (1.0f / 2048.0f) + 1e-5f);
    float4 w0 = *reinterpret_cast<const float4*>(w + t * 4);
    float4 w1 = *reinterpret_cast<const float4*>(w + 1024 + t * 4);
    u32* op = (u32*)(o + (long)row * 2048);
    op[t * 2]           = packbf(v0.x * inv * w0.x, v0.y * inv * w0.y);
    op[t * 2 + 1]       = packbf(v0.z * inv * w0.z, v0.w * inv * w0.w);
    op[512 + t * 2]     = packbf(v1.x * inv * w1.x, v1.y * inv * w1.y);
    op[512 + t * 2 + 1] = packbf(v1.z * inv * w1.z, v1.w * inv * w1.w);
}

// ---------------- fused: x += p0 + p1 ; h = rmsnorm(x) * w ----------------
__global__ void rmsadd2_kernel(float* __restrict__ x, const float* __restrict__ p0,
                               const float* __restrict__ p1, const float* __restrict__ w,
                               u16* __restrict__ o) {
    int row = blockIdx.x, t = threadIdx.x;
    long base = (long)row * 2048;
    float4 v0 = *reinterpret_cast<const float4*>(x + base + t * 4);
    float4 v1 = *reinterpret_cast<const float4*>(x + base + 1024 + t * 4);
    float4 a0 = *reinterpret_cast<const float4*>(p0 + base + t * 4);
    float4 a1 = *reinterpret_cast<const float4*>(p0 + base + 1024 + t * 4);
    float4 b0 = *reinterpret_cast<const float4*>(p1 + base + t * 4);
    float4 b1 = *reinterpret_cast<const float4*>(p1 + base + 1024 + t * 4);
    v0.x += a0.x + b0.x; v0.y += a0.y + b0.y; v0.z += a0.z + b0.z; v0.w += a0.w + b0.w;
    v1.x += a1.x + b1.x; v1.y += a1.y + b1.y; v1.z += a1.z + b1.z; v1.w += a1.w + b1.w;
    *reinterpret_cast<float4*>(x + base + t * 4) = v0;
    *reinterpret_cast<float4*>(x + base + 1024 + t * 4) = v1;
    float ss = v0.x * v0.x + v0.y * v0.y + v0.z * v0.z + v0.w * v0.w
             + v1.x * v1.x + v1.y * v1.y + v1.z * v1.z + v1.w * v1.w;
#pragma unroll
    for (int ofs = 32; ofs; ofs >>= 1) ss += __shfl_xor(ss, ofs);
    __shared__ float red[4];
    if ((t & 63) == 0) red[t >> 6] = ss;
    __syncthreads();
    ss = red[0] + red[1] + red[2] + red[3];
    float inv = 1.0f / sqrtf(ss * (1.0f / 2048.0f) + 1e-5f);
    float4 w0 = *reinterpret_cast<const float4*>(w + t * 4);
    float4 w1 = *reinterpret_cast<const float4*>(w + 1024 + t * 4);
    u32* op = (u32*)(o + (long)row * 2048);
    op[t * 2]           = packbf(v0.x * inv * w0.x, v0.y * inv * w0.y);
    op[t * 2 + 1]       = packbf(v0.z * inv * w0.z, v0.w * inv * w0.w);
    op[512 + t * 2]     = packbf(v1.x * inv * w1.x, v1.y * inv * w1.y);
    op[512 + t * 2 + 1] = packbf(v1.z * inv * w1.z, v1.w * inv * w1.w);
}

// ============ merged rope_q + build_k + build_vT (mutually independent) ============
__global__ void prep_attn_kernel(u16* __restrict__ qkv,
                                 const float* __restrict__ kc, const float* __restrict__ vc,
                                 u16* __restrict__ kf, u16* __restrict__ vfT) {
    int blk = blockIdx.x;
    int tid = threadIdx.x;
    if (blk < 4096) {
        int idx = blk * 256 + tid;
        int fi = idx & 63;
        int hh = (idx >> 6) & 15;
        int s = idx >> 10;
        u16* p = qkv + (long)s * 3072 + hh * 128 + fi;
        float q0 = bf2f(p[0]), q1 = bf2f(p[64]);
        float inv = exp2f((float)fi * -0.20762050593046014f);
        float ang = (float)(2048 + s) * inv;
        float sn, cs;
        sincosf(ang, &sn, &cs);
        p[0]  = (u16)bf16_1(q0 * cs - q1 * sn);
        p[64] = (u16)bf16_1(q1 * cs + q0 * sn);
    } else if (blk < 16384) {
        int local = blk - 4096;
        int bx = local % 768, hh = local / 768;
        int t = bx * 256 + tid;
        int fi = t & 63;
        int j = t >> 6;
        float k0, k1;
        if (j < 2048) {
            const float* kp = kc + ((long)hh * 2048 + j) * 128;
            k0 = kp[fi]; k1 = kp[fi + 64];
        } else {
            int s = j - 2048;
            const u16* kp = qkv + (long)s * 3072 + 2048 + (hh >> 2) * 128;
            k0 = bf2f(kp[fi]); k1 = bf2f(kp[fi + 64]);
        }
        float inv = exp2f((float)fi * -0.20762050593046014f);
        float ang = (float)j * inv;
        float sn, cs;
        sincosf(ang, &sn, &cs);
        u16* kd = kf + ((long)hh * 3072 + j) * 128;
        kd[fi]      = (u16)bf16_1(k0 * cs - k1 * sn);
        kd[fi + 64] = (u16)bf16_1(k1 * cs + k0 * sn);
    } else {
        __shared__ u16 tile[64][137];
        int local = blk - 16384;
        int bx = local % 48, hh = local / 48;
        int j0 = bx * 64;
        int d = tid & 127, jr = tid >> 7;
#pragma unroll
        for (int p = 0; p < 32; ++p) {
            int j = jr + p * 2;
            int gj = j0 + j;
            float v;
            if (gj < 2048) v = vc[((long)hh * 2048 + gj) * 128 + d];
            else           v = bf2f(qkv[(long)(gj - 2048) * 3072 + 2560 + (hh >> 2) * 128 + d]);
            tile[j][d] = (u16)bf16_1(v);
        }
        __syncthreads();
        int jp = tid & 31, dd = tid >> 5;
#pragma unroll
        for (int p = 0; p < 16; ++p) {
            int d2 = dd + p * 8;
            u32 w = (u32)tile[jp * 2][d2] | ((u32)tile[jp * 2 + 1][d2] << 16);
            ((u32*)vfT)[((long)hh * 128 + d2) * 1536 + (j0 >> 1) + jp] = w;
        }
    }
}

// ---------------- host ----------------
extern "C" void kernel_launch(void* const* d_in, const int* in_sizes, int n_in,
                              void* d_out, int out_size, void* d_ws, size_t ws_size,
                              hipStream_t stream) {
    const int*   ids   = (const int*)d_in[0];
    const float* kv    = (const float*)d_in[1];
    const float* emb   = (const float*)d_in[2];
    const float* Wq    = (const float*)d_in[3];
    const float* Wk    = (const float*)d_in[4];
    const float* Wv    = (const float*)d_in[5];
    const float* Wo    = (const float*)d_in[6];
    const float* ln1   = (const float*)d_in[7];
    const float* ln2   = (const float*)d_in[8];
    const float* Wg    = (const float*)d_in[9];
    const float* Wu    = (const float*)d_in[10];
    const float* Wd    = (const float*)d_in[11];
    const float* normw = (const float*)d_in[12];
    const float* lmh   = (const float*)d_in[13];
    float* out = (float*)d_out;
    (void)in_sizes; (void)n_in; (void)out_size; (void)ws_size;

    char* w = (char*)d_ws;
    u16*   wt     = (u16*)w;                      // per-layer bf16^T weights (90.2 MB)
    float* x      = (float*)(w + 90177536);       // [1024,2048] fp32 residual
    u16*   h      = (u16*)(w + 98566144);         // [1024,2048] bf16
    u16*   qkv    = (u16*)(w + 102760448);        // [1024,3072] bf16 (layers only)
    u16*   kf     = (u16*)(w + 109051904);        // [16,3072,128] bf16
    u16*   vfT    = (u16*)(w + 121634816);        // [16,128,3072] bf16
    float* partWo = (float*)(w + 134217728);      // 2x[1024,2048] fp32
    u16*   gu     = (u16*)(w + 134217728);        // [1024,5632] bf16 (after Wo reduce)
    float* partWd = (float*)(w + 157286400);      // 2x[1024,2048] fp32
    u16*   attn   = (u16*)(w + 174063616);        // [1024,2048] bf16 (flash reads qkv!)
    u16*   lmT    = (u16*)(w + 102760448);        // [32000][2048] bf16 post-layers (131 MB)

    u16* qkvT = wt;                 // [3072][2048]
    u16* WoT  = wt + 6291456;       // [2048][2048]
    u16* guT  = wt + 10485760;      // [11264][2048] (gate/up interleaved 32-row groups)
    u16* WdT  = wt + 33554432;      // [2048][5632]

    embed_rms_kernel<<<1024, 256, 0, stream>>>(ids, emb, ln1, x, h);

    for (int l = 0; l < 2; ++l) {
        const float* Wq_l = Wq + (long)l * 2048 * 2048;
        const float* Wk_l = Wk + (long)l * 2048 * 512;
        const float* Wv_l = Wv + (long)l * 2048 * 512;
        const float* Wo_l = Wo + (long)l * 2048 * 2048;
        const float* Wg_l = Wg + (long)l * 2048 * 5632;
        const float* Wu_l = Wu + (long)l * 2048 * 5632;
        const float* Wd_l = Wd + (long)l * 5632 * 2048;
        const float* kc = kv + (long)l * 16 * 2048 * 128;
        const float* vc = kv + (long)(2 + l) * 16 * 2048 * 128;

        convT_layer_kernel<<<11008, 256, 0, stream>>>(
            Wq_l, Wk_l, Wv_l, Wo_l, Wg_l, Wu_l, Wd_l, qkvT, WoT, guT, WdT);

        // fused QKV projection: [1024,3072] on the 8-phase 128x128 engine
        bgemm_kernel<u16><<<dim3(8, 24, 1), 256, 0, stream>>>(
            h, 2048, 0, qkvT, 2048, 0, qkv, 3072, 0, 2048);
        // rope(q) + build K + build V^T in one launch
        prep_attn_kernel<<<17152, 256, 0, stream>>>(qkv, kc, vc, kf, vfT);

        // fused attention (scores+mask+softmax+PV), staged K/V
        flash_kernel<<<dim3(32, 16), 128, 0, stream>>>(qkv, kf, vfT, attn);

        // Wo with split-K, partials then fused add+rmsnorm(ln2)
        bgemm_kernel<float><<<dim3(8, 16, 2), 256, 0, stream>>>(
            attn, 2048, 1024, WoT, 2048, 1024,
            partWo, 2048, (long)1024 * 2048, 1024);
        rmsadd2_kernel<<<1024, 256, 0, stream>>>(x, partWo, partWo + 2097152, ln2 + l * 2048, h);

        // fused gate+up+SiLU on the 8-phase 128x128 engine (704 blocks)
        bgemm_kernel<u16, true><<<dim3(8, 88, 1), 256, 0, stream>>>(
            h, 2048, 0, guT, 2048, 0, gu, 5632, 0, 2048);

        // Wd with split-K, partials then fused add+rmsnorm(next norm weight)
        bgemm_kernel<float><<<dim3(8, 16, 2), 256, 0, stream>>>(
            gu, 5632, 2816, WdT, 5632, 2816,
            partWd, 2048, (long)1024 * 2048, 2816);
        rmsadd2_kernel<<<1024, 256, 0, stream>>>(
            x, partWd, partWd + 2097152, (l == 0) ? (ln1 + 2048) : normw, h);
    }

    // lm_head on the 8-phase 256x256 engine (best measured at this shape)
    convT_kernel<<<dim3(500, 32), 256, 0, stream>>>(lmh, 32000, 0, lmT, 2048);
    bgemm256_kernel<float><<<dim3(4, 125), 512, 0, stream>>>(
        h, 2048, lmT, 2048, out, 32000, 2048);
}